// Round 7
// baseline (283.881 us; speedup 1.0000x reference)
//
#include <hip/hip_runtime.h>
#include <cstdint>
#include <cstddef>
#include <math.h>

typedef __attribute__((ext_vector_type(8))) __bf16 bf16x8;
typedef __attribute__((ext_vector_type(4))) __bf16 bf16x4;
typedef __attribute__((ext_vector_type(4))) float f32x4;

#define AS1 __attribute__((address_space(1)))
#define AS3 __attribute__((address_space(3)))

#define LOG2E 1.4426950408889634f

__device__ __forceinline__ void gld16(void* lds_uniform, const void* gaddr) {
  __builtin_amdgcn_global_load_lds((const AS1 unsigned int*)gaddr,
                                   (AS3 unsigned int*)lds_uniform, 16, 0, 0);
}

// ---------------------------------------------------------------- fp32->bf16 (3 arrays, 1 launch)
__global__ __launch_bounds__(256)
void cvt_all_kernel(const float* __restrict__ x, const float* __restrict__ wqkv,
                    const float* __restrict__ wproj,
                    __bf16* __restrict__ xb, __bf16* __restrict__ wqkvb,
                    __bf16* __restrict__ wprojb) {
  const int b = blockIdx.x;
  const float* src; __bf16* dst; int off;
  if (b < 4096)      { src = x;     dst = xb;     off = b; }
  else if (b < 7168) { src = wqkv;  dst = wqkvb;  off = b - 4096; }
  else               { src = wproj; dst = wprojb; off = b - 7168; }
  const int i = (off * 256 + threadIdx.x) * 4;
  const float4 v = *(const float4*)(src + i);
  bf16x4 o;
  o[0] = (__bf16)v.x; o[1] = (__bf16)v.y; o[2] = (__bf16)v.z; o[3] = (__bf16)v.w;
  *(bf16x4*)(dst + i) = o;
}

// ---------------------------------------------------------------- QKV GEMM (R6 swapped-operand epilogue)
__global__ __launch_bounds__(256, 2)
void gemm_qkv_kernel(const __bf16* __restrict__ A, const __bf16* __restrict__ B,
                     const float* __restrict__ q_bias, const float* __restrict__ v_bias,
                     const float* __restrict__ scale_mul,
                     __bf16* __restrict__ qb, __bf16* __restrict__ ktp, __bf16* __restrict__ vb) {
  __shared__ __attribute__((aligned(16))) __bf16 As[128 * 32];
  __shared__ __attribute__((aligned(16))) __bf16 Bs[128 * 32];
  const int tid = threadIdx.x;
  const int w = tid >> 6, lane = tid & 63;
  const int m0 = blockIdx.y * 128, n0 = blockIdx.x * 128;
  const int wm = (w >> 1) * 64, wn = (w & 1) * 64;
  const int c = lane & 15, g = lane >> 4;
  f32x4 acc[4][4];  // [ni][mi]
#pragma unroll
  for (int i = 0; i < 4; ++i)
#pragma unroll
    for (int j = 0; j < 4; ++j) acc[i][j] = (f32x4)(0.0f);

  const int r_row = lane >> 2;
  const int r_col = (lane & 3) * 16;
  const char* Abase = (const char*)A + (size_t)m0 * 2048;
  const char* Bbase = (const char*)B + (size_t)n0 * 2048;

  for (int kt = 0; kt < 1024; kt += 32) {
#pragma unroll
    for (int s = 0; s < 2; ++s) {
      const int R = w * 2 + s;
      const int row = R * 16 + r_row;
      gld16((char*)As + R * 1024, Abase + (size_t)row * 2048 + kt * 2 + r_col);
      gld16((char*)Bs + R * 1024, Bbase + (size_t)row * 2048 + kt * 2 + r_col);
    }
    __syncthreads();
    bf16x8 af[4], bfr[4];
#pragma unroll
    for (int i = 0; i < 4; ++i) {
      af[i]  = *(const bf16x8*)((const char*)As + (wm + i * 16 + c) * 64 + g * 16);
      bfr[i] = *(const bf16x8*)((const char*)Bs + (wn + i * 16 + c) * 64 + g * 16);
    }
#pragma unroll
    for (int ni = 0; ni < 4; ++ni)
#pragma unroll
      for (int mi = 0; mi < 4; ++mi)
        acc[ni][mi] = __builtin_amdgcn_mfma_f32_16x16x32_bf16(bfr[ni], af[mi], acc[ni][mi], 0, 0, 0);
    __syncthreads();
  }

  const int nbase = n0 + wn;
  const int which = nbase >> 10;
  const int h = (nbase >> 6) & 15;
  float smh = 1.0f;
  if (which == 0) smh = __expf(fminf(scale_mul[h], 4.605170185988091f)) * LOG2E;
  float4 cb[4];
#pragma unroll
  for (int ni = 0; ni < 4; ++ni) {
    if (which == 0)      cb[ni] = *(const float4*)(q_bias + nbase + ni * 16 + 4 * g);
    else if (which == 2) cb[ni] = *(const float4*)(v_bias + nbase - 2048 + ni * 16 + 4 * g);
    else                 cb[ni] = make_float4(0.f, 0.f, 0.f, 0.f);
  }
  const int mrow0 = m0 + wm;
  const int b2 = mrow0 >> 11;
  const int lpos0 = mrow0 & 2047;
  __bf16* kt_tile = ktp + (size_t)(b2 * 16 + h) * 131072 + (size_t)(lpos0 >> 6) * 4096;
  __bf16* dst_qv = ((which == 0) ? qb : vb) + ((size_t)((b2 * 16 + h) * 2048 + lpos0)) * 64;

#pragma unroll
  for (int mi = 0; mi < 4; ++mi) {
    float v[4][4];
    float ss = 0.0f;
#pragma unroll
    for (int ni = 0; ni < 4; ++ni) {
      v[ni][0] = acc[ni][mi][0] + cb[ni].x;
      v[ni][1] = acc[ni][mi][1] + cb[ni].y;
      v[ni][2] = acc[ni][mi][2] + cb[ni].z;
      v[ni][3] = acc[ni][mi][3] + cb[ni].w;
#pragma unroll
      for (int j = 0; j < 4; ++j) ss += v[ni][j] * v[ni][j];
    }
    ss += __shfl_xor(ss, 16, 64);
    ss += __shfl_xor(ss, 32, 64);
    const float sc = (which == 2) ? 1.0f : (rsqrtf(ss) * smh);
    const int key = mi * 16 + c;
    if (which == 1) {
#pragma unroll
      for (int ni = 0; ni < 4; ++ni) {
        bf16x4 pk;
        pk[0] = (__bf16)(v[ni][0] * sc); pk[1] = (__bf16)(v[ni][1] * sc);
        pk[2] = (__bf16)(v[ni][2] * sc); pk[3] = (__bf16)(v[ni][3] * sc);
        *(bf16x4*)(kt_tile + (ni >> 1) * 2048 + key * 32 + (ni & 1) * 16 + 4 * g) = pk;
      }
    } else {
      __bf16* drow = dst_qv + (size_t)key * 64;
#pragma unroll
      for (int ni = 0; ni < 4; ++ni) {
        bf16x4 pk;
        pk[0] = (__bf16)(v[ni][0] * sc); pk[1] = (__bf16)(v[ni][1] * sc);
        pk[2] = (__bf16)(v[ni][2] * sc); pk[3] = (__bf16)(v[ni][3] * sc);
        *(bf16x4*)(drow + ni * 16 + 4 * g) = pk;
      }
    }
  }
}

// ---------------------------------------------------------------- V transpose to tile-slot layout
__global__ __launch_bounds__(256)
void vtrans_kernel(const __bf16* __restrict__ vb, __bf16* __restrict__ vtp) {
  __shared__ __attribute__((aligned(16))) __bf16 Vs[4][64 * 64];
  const int w = threadIdx.x >> 6, lane = threadIdx.x & 63;
  const int idx = blockIdx.x * 4 + w;
  const int bh = idx >> 5, tile = idx & 31;
  const __bf16* src = vb + ((size_t)bh * 2048 + tile * 64) * 64;
#pragma unroll
  for (int s = 0; s < 8; ++s)
    gld16((char*)&Vs[w][0] + s * 1024, (const char*)src + s * 1024 + lane * 16);
  __syncthreads();
  __bf16* outb = vtp + (size_t)idx * 4096;
#pragma unroll
  for (int r = 0; r < 8; ++r) {
    const int o = r * 512 + lane * 8;
    const int hd = (o >> 5) & 63;
    const int sl0 = ((o >> 11) << 5) | (o & 31);
    bf16x8 pk;
#pragma unroll
    for (int i = 0; i < 8; ++i) {
      const int slot = sl0 + i;
      const int key = (slot & 3) * 16 + (slot >> 2);
      pk[i] = Vs[w][key * 64 + hd];
    }
    *(bf16x8*)(outb + o) = pk;
  }
}

// ---------------------------------------------------------------- bias rearrange (coalesced, LDS-tiled)
__global__ __launch_bounds__(256)
void btrans_kernel(const float* __restrict__ bias, __bf16* __restrict__ btr) {
  __shared__ __bf16 T[32][264];
  const int tid = threadIdx.x;
  const int rb = blockIdx.x >> 3, cg = blockIdx.x & 7;
  const float* src = bias + (size_t)(rb * 32) * 2048 + cg * 256;
#pragma unroll
  for (int i = 0; i < 8; ++i) {
    const int u = i * 256 + tid;
    const int r = u >> 6, c4 = (u & 63) * 4;
    const float4 v = *(const float4*)(src + (size_t)r * 2048 + c4);
    T[r][c4 + 0] = (__bf16)(v.x * LOG2E);
    T[r][c4 + 1] = (__bf16)(v.y * LOG2E);
    T[r][c4 + 2] = (__bf16)(v.z * LOG2E);
    T[r][c4 + 3] = (__bf16)(v.w * LOG2E);
  }
  __syncthreads();
  const int ktl = tid >> 6;
  const int lane = tid & 63, g = lane >> 4, c = lane & 15;
  __bf16 outv[32];
#pragma unroll
  for (int v = 0; v < 32; ++v) {
    const int mi = v >> 4, ni = (v >> 2) & 3, j = v & 3;
    outv[v] = T[mi * 16 + g * 4 + j][ktl * 64 + ni * 16 + c];
  }
  __bf16* dst = btr + ((size_t)(rb * 32 + cg * 4 + ktl) * 64 + lane) * 32;
#pragma unroll
  for (int i = 0; i < 4; ++i)
    *(bf16x8*)(dst + i * 8) = *(bf16x8*)(outv + i * 8);
}

// ---------------------------------------------------------------- flash attention v8
// 64 q-rows per wave (mi=0..3), KT=64, K-split x2, dbuf K, JIT bias/vf, per-mi sacc.
#define LOADK(t, K) {                                                          \
  const char* _b = kp + (size_t)(t) * 8192 + laneoff;                          \
  _Pragma("unroll")                                                            \
  for (int f = 0; f < 8; ++f)                                                  \
    K[f] = *(const bf16x8*)(_b + (f & 1) * 4096 + (f >> 1) * 1024);            \
}

__global__ __launch_bounds__(64, 2)
void attn_kernel(const __bf16* __restrict__ qb, const __bf16* __restrict__ ktp,
                 const __bf16* __restrict__ vtp, const __bf16* __restrict__ btr,
                 float* __restrict__ pO, float* __restrict__ pl) {
  __shared__ __attribute__((aligned(16))) __bf16 Ps[2][64][32];  // 8KB, wave-private
  const int lane = threadIdx.x;
  const int c = lane & 15, g = lane >> 4;
  const int idx = blockIdx.x;                       // half*1024 + rt*32 + bh
  const int bh = idx & 31, rt = (idx >> 5) & 31, half = idx >> 10;
  const __bf16* qh = qb + (size_t)bh * (2048 * 64);
  const char* kp = (const char*)ktp + (size_t)bh * (32 * 8192);
  const char* vp = (const char*)vtp + (size_t)bh * (32 * 8192);
  const char* bp = (const char*)btr + (size_t)(rt * 2) * 131072;  // rb slab = 128KB
  const int q0 = rt * 64;
  const int laneoff = c * 64 + g * 16;

  bf16x8 qf[4][2];
#pragma unroll
  for (int mi = 0; mi < 4; ++mi)
#pragma unroll
    for (int ks = 0; ks < 2; ++ks)
      qf[mi][ks] = *(const bf16x8*)(qh + (size_t)(q0 + mi * 16 + c) * 64 + ks * 32 + g * 8);

  f32x4 oacc[4][4];
  float lsum[4][4];
#pragma unroll
  for (int mi = 0; mi < 4; ++mi)
#pragma unroll
    for (int ni = 0; ni < 4; ++ni) oacc[mi][ni] = (f32x4)(0.0f);
#pragma unroll
  for (int mi = 0; mi < 4; ++mi)
#pragma unroll
    for (int j = 0; j < 4; ++j) lsum[mi][j] = 0.0f;

  const int t0 = half * 16;
  bf16x8 kA[8], kB[8];
  LOADK(t0, kA);
#pragma unroll 1
  for (int tt = 0; tt < 16; tt += 2) {
#pragma unroll
    for (int sub = 0; sub < 2; ++sub) {
      const int t = t0 + tt + sub;
      bf16x8* K  = sub ? kB : kA;
      bf16x8* Kn = sub ? kA : kB;
      const int tn = (t + 1) & 31;
      // QK + softmax, per-mi (sacc transient: 16 regs)
#pragma unroll
      for (int mi = 0; mi < 4; ++mi) {
        f32x4 sacc[4];
#pragma unroll
        for (int ni = 0; ni < 4; ++ni) {
          f32x4 s_ = __builtin_amdgcn_mfma_f32_16x16x32_bf16(qf[mi][0], K[ni * 2 + 0], (f32x4)(0.0f), 0, 0, 0);
          sacc[ni] = __builtin_amdgcn_mfma_f32_16x16x32_bf16(qf[mi][1], K[ni * 2 + 1], s_, 0, 0, 0);
        }
        // JIT bias for (t, mi): 32B = 16 vals (ni*4+j), rb = rt*2 + (mi>>1)
        const char* _bb = bp + (size_t)(mi >> 1) * 131072 +
                          (((size_t)t * 64 + lane) * 64) + (mi & 1) * 32;
        const bf16x8 b0 = *(const bf16x8*)_bb;
        const bf16x8 b1 = *(const bf16x8*)(_bb + 16);
        if (mi == 0) LOADK(tn, Kn);   // prefetch next tile while softmax of mi 0..3 runs
#pragma unroll
        for (int j = 0; j < 4; ++j) {
          const float p0 = __builtin_amdgcn_exp2f(sacc[0][j] + (float)b0[j]);
          const float p1 = __builtin_amdgcn_exp2f(sacc[1][j] + (float)b0[4 + j]);
          const float p2 = __builtin_amdgcn_exp2f(sacc[2][j] + (float)b1[j]);
          const float p3 = __builtin_amdgcn_exp2f(sacc[3][j] + (float)b1[4 + j]);
          lsum[mi][j] += (p0 + p1) + (p2 + p3);
          bf16x4 pk;
          pk[0] = (__bf16)p0; pk[1] = (__bf16)p1; pk[2] = (__bf16)p2; pk[3] = (__bf16)p3;
          *(bf16x4*)&Ps[c >> 3][mi * 16 + g * 4 + j][(c & 7) * 4] = pk;
        }
      }
      // O += P V : pf from per-wave LDS, vf JIT per ni
      bf16x8 pf[4][2];
#pragma unroll
      for (int mi = 0; mi < 4; ++mi)
#pragma unroll
        for (int ks = 0; ks < 2; ++ks)
          pf[mi][ks] = *(const bf16x8*)&Ps[ks][mi * 16 + c][g * 8];
      const char* _vb = vp + (size_t)t * 8192 + laneoff;
#pragma unroll
      for (int ni = 0; ni < 4; ++ni) {
        const bf16x8 v0 = *(const bf16x8*)(_vb + ((ni * 2 + 0) & 1) * 4096 + ((ni * 2 + 0) >> 1) * 1024);
        const bf16x8 v1 = *(const bf16x8*)(_vb + ((ni * 2 + 1) & 1) * 4096 + ((ni * 2 + 1) >> 1) * 1024);
#pragma unroll
        for (int mi = 0; mi < 4; ++mi) {
          oacc[mi][ni] = __builtin_amdgcn_mfma_f32_16x16x32_bf16(pf[mi][0], v0, oacc[mi][ni], 0, 0, 0);
          oacc[mi][ni] = __builtin_amdgcn_mfma_f32_16x16x32_bf16(pf[mi][1], v1, oacc[mi][ni], 0, 0, 0);
        }
      }
    }
  }

  // disjoint partial stores: pO[half][bh][2048 rows][64], pl[half][bh][2048]
  float* po  = pO + (((size_t)(half * 32 + bh)) * 2048 + q0) * 64;
  float* plp = pl + ((size_t)(half * 32 + bh)) * 2048 + q0;
#pragma unroll
  for (int mi = 0; mi < 4; ++mi)
#pragma unroll
    for (int j = 0; j < 4; ++j) {
      float l = lsum[mi][j];
      l += __shfl_xor(l, 1, 64);
      l += __shfl_xor(l, 2, 64);
      l += __shfl_xor(l, 4, 64);
      l += __shfl_xor(l, 8, 64);
      const int row = mi * 16 + g * 4 + j;
      if (c == 0) plp[row] = l;
#pragma unroll
      for (int ni = 0; ni < 4; ++ni)
        po[row * 64 + ni * 16 + c] = oacc[mi][ni][j];
    }
}

// ---------------------------------------------------------------- combine halves -> oupb bf16
__global__ __launch_bounds__(256)
void combine_kernel(const float* __restrict__ pO, const float* __restrict__ pl,
                    __bf16* __restrict__ oupb) {
  const int rg = blockIdx.x;                 // bh*? : rg = qt*32 + bh? use bh = rg&31, qt = rg>>5
  const int bh = rg & 31, qt = rg >> 5;      // qt in [0,64): 32-row groups
  const int b2 = bh >> 4, h = bh & 15;
  const int tid = threadIdx.x;
  const int row = qt * 32 + (tid >> 3), hd0 = (tid & 7) * 8;
  const float l = pl[(size_t)bh * 2048 + row] + pl[(size_t)(32 + bh) * 2048 + row];
  const float inv = 1.0f / l;
  const float* p0 = pO + ((size_t)bh * 2048 + row) * 64 + hd0;
  const float* p1 = pO + ((size_t)(32 + bh) * 2048 + row) * 64 + hd0;
  const float4 a0 = *(const float4*)p0;
  const float4 b0 = *(const float4*)(p0 + 4);
  const float4 a1 = *(const float4*)p1;
  const float4 b1 = *(const float4*)(p1 + 4);
  bf16x8 o;
  o[0] = (__bf16)((a0.x + a1.x) * inv); o[1] = (__bf16)((a0.y + a1.y) * inv);
  o[2] = (__bf16)((a0.z + a1.z) * inv); o[3] = (__bf16)((a0.w + a1.w) * inv);
  o[4] = (__bf16)((b0.x + b1.x) * inv); o[5] = (__bf16)((b0.y + b1.y) * inv);
  o[6] = (__bf16)((b0.z + b1.z) * inv); o[7] = (__bf16)((b0.w + b1.w) * inv);
  *(bf16x8*)(oupb + ((size_t)(b2 * 2048 + row) * 16 + h) * 64 + hd0) = o;
}

// ---------------------------------------------------------------- proj GEMM (64x128 tiles)
__global__ __launch_bounds__(256, 2)
void gemm_proj_kernel(const __bf16* __restrict__ A, const __bf16* __restrict__ B,
                      const float* __restrict__ b_proj, float* __restrict__ out) {
  __shared__ __attribute__((aligned(16))) __bf16 As[64 * 32];
  __shared__ __attribute__((aligned(16))) __bf16 Bs[128 * 32];
  const int tid = threadIdx.x;
  const int w = tid >> 6, lane = tid & 63;
  const int c = lane & 15, g = lane >> 4;
  const int m0 = blockIdx.y * 64, n0 = blockIdx.x * 128;
  const int wm = (w >> 1) * 32, wn = (w & 1) * 64;
  f32x4 acc[2][4];
#pragma unroll
  for (int i = 0; i < 2; ++i)
#pragma unroll
    for (int j = 0; j < 4; ++j) acc[i][j] = (f32x4)(0.0f);

  const int r_row = lane >> 2;
  const int r_col = (lane & 3) * 16;
  const char* Abase = (const char*)A + (size_t)m0 * 2048;
  const char* Bbase = (const char*)B + (size_t)n0 * 2048;

  for (int kt = 0; kt < 1024; kt += 32) {
    {
      const int row = w * 16 + r_row;
      gld16((char*)As + w * 1024, Abase + (size_t)row * 2048 + kt * 2 + r_col);
    }
#pragma unroll
    for (int s = 0; s < 2; ++s) {
      const int R = w * 2 + s;
      const int row = R * 16 + r_row;
      gld16((char*)Bs + R * 1024, Bbase + (size_t)row * 2048 + kt * 2 + r_col);
    }
    __syncthreads();
    bf16x8 af[2], bfr[4];
#pragma unroll
    for (int i = 0; i < 2; ++i)
      af[i] = *(const bf16x8*)((const char*)As + (wm + i * 16 + c) * 64 + g * 16);
#pragma unroll
    for (int i = 0; i < 4; ++i)
      bfr[i] = *(const bf16x8*)((const char*)Bs + (wn + i * 16 + c) * 64 + g * 16);
#pragma unroll
    for (int mi = 0; mi < 2; ++mi)
#pragma unroll
      for (int ni = 0; ni < 4; ++ni)
        acc[mi][ni] = __builtin_amdgcn_mfma_f32_16x16x32_bf16(af[mi], bfr[ni], acc[mi][ni], 0, 0, 0);
    __syncthreads();
  }

  float cbias[4];
#pragma unroll
  for (int ni = 0; ni < 4; ++ni) cbias[ni] = b_proj[n0 + wn + ni * 16 + c];
#pragma unroll
  for (int mi = 0; mi < 2; ++mi)
#pragma unroll
    for (int j = 0; j < 4; ++j) {
      const int m = m0 + wm + mi * 16 + g * 4 + j;
      float* orow = out + (size_t)m * 1024 + n0 + wn;
#pragma unroll
      for (int ni = 0; ni < 4; ++ni)
        orow[ni * 16 + c] = acc[mi][ni][j] + cbias[ni];
    }
}

// ---------------------------------------------------------------- launch
extern "C" void kernel_launch(void* const* d_in, const int* in_sizes, int n_in,
                              void* d_out, int out_size, void* d_ws, size_t ws_size,
                              hipStream_t stream) {
  const float* x         = (const float*)d_in[0];
  const float* attn_bias = (const float*)d_in[1];
  const float* w_qkv     = (const float*)d_in[2];
  const float* q_bias    = (const float*)d_in[3];
  const float* v_bias    = (const float*)d_in[4];
  const float* scale_mul = (const float*)d_in[5];
  const float* w_proj    = (const float*)d_in[6];
  const float* b_proj    = (const float*)d_in[7];
  float* out = (float*)d_out;

  __bf16* xb     = (__bf16*)d_ws;                 // 8MB (aliased as oupb after gemm_qkv)
  __bf16* wqkvb  = xb + 4194304;                  // 6MB
  __bf16* wprojb = wqkvb + 3145728;               // 2MB
  __bf16* qb     = wprojb + 1048576;              // 8MB (q pre-scaled by log2e)
  __bf16* ktp    = qb + 4194304;                  // 8MB (K fragment-tile order)
  __bf16* vtp    = ktp + 4194304;                 // 8MB (V slot order)
  __bf16* btr    = vtp + 4194304;                 // 8MB (bias, *log2e)
  __bf16* vb     = btr + 4194304;                 // 8MB (V row order; dead after vtrans)
  float*  pO     = (float*)vb;                    // 32MB, aliases vb (attn runs after vtrans)
  float*  pl     = pO + 2 * 32 * 2048 * 64;       // 512KB
  __bf16* oupb   = xb;                            // alias: xb dead after gemm_qkv

  btrans_kernel<<<512, 256, 0, stream>>>(attn_bias, btr);
  cvt_all_kernel<<<8192, 256, 0, stream>>>(x, w_qkv, w_proj, xb, wqkvb, wprojb);

  gemm_qkv_kernel<<<dim3(24, 32), 256, 0, stream>>>(xb, wqkvb, q_bias, v_bias, scale_mul,
                                                    qb, ktp, vb);
  vtrans_kernel<<<256, 256, 0, stream>>>(vb, vtp);
  attn_kernel<<<2048, 64, 0, stream>>>(qb, ktp, vtp, btr, pO, pl);
  combine_kernel<<<2048, 256, 0, stream>>>(pO, pl, oupb);
  gemm_proj_kernel<<<dim3(8, 64), 256, 0, stream>>>(oupb, wprojb, b_proj, out);
}

// Round 8
// 228.443 us; speedup vs baseline: 1.2427x; 1.2427x over previous
//
#include <hip/hip_runtime.h>
#include <cstdint>
#include <cstddef>
#include <math.h>

typedef __attribute__((ext_vector_type(8))) __bf16 bf16x8;
typedef __attribute__((ext_vector_type(4))) __bf16 bf16x4;
typedef __attribute__((ext_vector_type(4))) float f32x4;

#define AS1 __attribute__((address_space(1)))
#define AS3 __attribute__((address_space(3)))

#define LOG2E 1.4426950408889634f

__device__ __forceinline__ void gld16(void* lds_uniform, const void* gaddr) {
  __builtin_amdgcn_global_load_lds((const AS1 unsigned int*)gaddr,
                                   (AS3 unsigned int*)lds_uniform, 16, 0, 0);
}

// ---------------------------------------------------------------- fp32->bf16 (3 arrays, 1 launch)
__global__ __launch_bounds__(256)
void cvt_all_kernel(const float* __restrict__ x, const float* __restrict__ wqkv,
                    const float* __restrict__ wproj,
                    __bf16* __restrict__ xb, __bf16* __restrict__ wqkvb,
                    __bf16* __restrict__ wprojb) {
  const int b = blockIdx.x;
  const float* src; __bf16* dst; int off;
  if (b < 4096)      { src = x;     dst = xb;     off = b; }
  else if (b < 7168) { src = wqkv;  dst = wqkvb;  off = b - 4096; }
  else               { src = wproj; dst = wprojb; off = b - 7168; }
  const int i = (off * 256 + threadIdx.x) * 4;
  const float4 v = *(const float4*)(src + i);
  bf16x4 o;
  o[0] = (__bf16)v.x; o[1] = (__bf16)v.y; o[2] = (__bf16)v.z; o[3] = (__bf16)v.w;
  *(bf16x4*)(dst + i) = o;
}

// ---------------------------------------------------------------- QKV GEMM (swapped-operand epilogue)
__global__ __launch_bounds__(256, 2)
void gemm_qkv_kernel(const __bf16* __restrict__ A, const __bf16* __restrict__ B,
                     const float* __restrict__ q_bias, const float* __restrict__ v_bias,
                     const float* __restrict__ scale_mul,
                     __bf16* __restrict__ qb, __bf16* __restrict__ ktp, __bf16* __restrict__ vb) {
  __shared__ __attribute__((aligned(16))) __bf16 As[128 * 32];
  __shared__ __attribute__((aligned(16))) __bf16 Bs[128 * 32];
  const int tid = threadIdx.x;
  const int w = tid >> 6, lane = tid & 63;
  const int m0 = blockIdx.y * 128, n0 = blockIdx.x * 128;
  const int wm = (w >> 1) * 64, wn = (w & 1) * 64;
  const int c = lane & 15, g = lane >> 4;
  f32x4 acc[4][4];  // [ni][mi]
#pragma unroll
  for (int i = 0; i < 4; ++i)
#pragma unroll
    for (int j = 0; j < 4; ++j) acc[i][j] = (f32x4)(0.0f);

  const int r_row = lane >> 2;
  const int r_col = (lane & 3) * 16;
  const char* Abase = (const char*)A + (size_t)m0 * 2048;
  const char* Bbase = (const char*)B + (size_t)n0 * 2048;

  for (int kt = 0; kt < 1024; kt += 32) {
#pragma unroll
    for (int s = 0; s < 2; ++s) {
      const int R = w * 2 + s;
      const int row = R * 16 + r_row;
      gld16((char*)As + R * 1024, Abase + (size_t)row * 2048 + kt * 2 + r_col);
      gld16((char*)Bs + R * 1024, Bbase + (size_t)row * 2048 + kt * 2 + r_col);
    }
    __syncthreads();
    bf16x8 af[4], bfr[4];
#pragma unroll
    for (int i = 0; i < 4; ++i) {
      af[i]  = *(const bf16x8*)((const char*)As + (wm + i * 16 + c) * 64 + g * 16);
      bfr[i] = *(const bf16x8*)((const char*)Bs + (wn + i * 16 + c) * 64 + g * 16);
    }
#pragma unroll
    for (int ni = 0; ni < 4; ++ni)
#pragma unroll
      for (int mi = 0; mi < 4; ++mi)
        acc[ni][mi] = __builtin_amdgcn_mfma_f32_16x16x32_bf16(bfr[ni], af[mi], acc[ni][mi], 0, 0, 0);
    __syncthreads();
  }

  const int nbase = n0 + wn;
  const int which = nbase >> 10;
  const int h = (nbase >> 6) & 15;
  float smh = 1.0f;
  if (which == 0) smh = __expf(fminf(scale_mul[h], 4.605170185988091f)) * LOG2E;
  float4 cb[4];
#pragma unroll
  for (int ni = 0; ni < 4; ++ni) {
    if (which == 0)      cb[ni] = *(const float4*)(q_bias + nbase + ni * 16 + 4 * g);
    else if (which == 2) cb[ni] = *(const float4*)(v_bias + nbase - 2048 + ni * 16 + 4 * g);
    else                 cb[ni] = make_float4(0.f, 0.f, 0.f, 0.f);
  }
  const int mrow0 = m0 + wm;
  const int b2 = mrow0 >> 11;
  const int lpos0 = mrow0 & 2047;
  __bf16* kt_tile = ktp + (size_t)(b2 * 16 + h) * 131072 + (size_t)(lpos0 >> 6) * 4096;
  __bf16* dst_qv = ((which == 0) ? qb : vb) + ((size_t)((b2 * 16 + h) * 2048 + lpos0)) * 64;

#pragma unroll
  for (int mi = 0; mi < 4; ++mi) {
    float v[4][4];
    float ss = 0.0f;
#pragma unroll
    for (int ni = 0; ni < 4; ++ni) {
      v[ni][0] = acc[ni][mi][0] + cb[ni].x;
      v[ni][1] = acc[ni][mi][1] + cb[ni].y;
      v[ni][2] = acc[ni][mi][2] + cb[ni].z;
      v[ni][3] = acc[ni][mi][3] + cb[ni].w;
#pragma unroll
      for (int j = 0; j < 4; ++j) ss += v[ni][j] * v[ni][j];
    }
    ss += __shfl_xor(ss, 16, 64);
    ss += __shfl_xor(ss, 32, 64);
    const float sc = (which == 2) ? 1.0f : (rsqrtf(ss) * smh);
    const int key = mi * 16 + c;
    if (which == 1) {
#pragma unroll
      for (int ni = 0; ni < 4; ++ni) {
        bf16x4 pk;
        pk[0] = (__bf16)(v[ni][0] * sc); pk[1] = (__bf16)(v[ni][1] * sc);
        pk[2] = (__bf16)(v[ni][2] * sc); pk[3] = (__bf16)(v[ni][3] * sc);
        *(bf16x4*)(kt_tile + (ni >> 1) * 2048 + key * 32 + (ni & 1) * 16 + 4 * g) = pk;
      }
    } else {
      __bf16* drow = dst_qv + (size_t)key * 64;
#pragma unroll
      for (int ni = 0; ni < 4; ++ni) {
        bf16x4 pk;
        pk[0] = (__bf16)(v[ni][0] * sc); pk[1] = (__bf16)(v[ni][1] * sc);
        pk[2] = (__bf16)(v[ni][2] * sc); pk[3] = (__bf16)(v[ni][3] * sc);
        *(bf16x4*)(drow + ni * 16 + 4 * g) = pk;
      }
    }
  }
}

// ---------------------------------------------------------------- V transpose to tile-slot layout
__global__ __launch_bounds__(256)
void vtrans_kernel(const __bf16* __restrict__ vb, __bf16* __restrict__ vtp) {
  __shared__ __attribute__((aligned(16))) __bf16 Vs[4][64 * 64];
  const int w = threadIdx.x >> 6, lane = threadIdx.x & 63;
  const int idx = blockIdx.x * 4 + w;
  const int bh = idx >> 5, tile = idx & 31;
  const __bf16* src = vb + ((size_t)bh * 2048 + tile * 64) * 64;
#pragma unroll
  for (int s = 0; s < 8; ++s)
    gld16((char*)&Vs[w][0] + s * 1024, (const char*)src + s * 1024 + lane * 16);
  __syncthreads();
  __bf16* outb = vtp + (size_t)idx * 4096;
#pragma unroll
  for (int r = 0; r < 8; ++r) {
    const int o = r * 512 + lane * 8;
    const int hd = (o >> 5) & 63;
    const int sl0 = ((o >> 11) << 5) | (o & 31);
    bf16x8 pk;
#pragma unroll
    for (int i = 0; i < 8; ++i) {
      const int slot = sl0 + i;
      const int key = (slot & 3) * 16 + (slot >> 2);
      pk[i] = Vs[w][key * 64 + hd];
    }
    *(bf16x8*)(outb + o) = pk;
  }
}

// ---------------------------------------------------------------- bias rearrange (coalesced, LDS-tiled)
__global__ __launch_bounds__(256)
void btrans_kernel(const float* __restrict__ bias, __bf16* __restrict__ btr) {
  __shared__ __bf16 T[32][264];
  const int tid = threadIdx.x;
  const int rb = blockIdx.x >> 3, cg = blockIdx.x & 7;
  const float* src = bias + (size_t)(rb * 32) * 2048 + cg * 256;
#pragma unroll
  for (int i = 0; i < 8; ++i) {
    const int u = i * 256 + tid;
    const int r = u >> 6, c4 = (u & 63) * 4;
    const float4 v = *(const float4*)(src + (size_t)r * 2048 + c4);
    T[r][c4 + 0] = (__bf16)(v.x * LOG2E);
    T[r][c4 + 1] = (__bf16)(v.y * LOG2E);
    T[r][c4 + 2] = (__bf16)(v.z * LOG2E);
    T[r][c4 + 3] = (__bf16)(v.w * LOG2E);
  }
  __syncthreads();
  const int ktl = tid >> 6;
  const int lane = tid & 63, g = lane >> 4, c = lane & 15;
  __bf16 outv[32];
#pragma unroll
  for (int v = 0; v < 32; ++v) {
    const int mi = v >> 4, ni = (v >> 2) & 3, j = v & 3;
    outv[v] = T[mi * 16 + g * 4 + j][ktl * 64 + ni * 16 + c];
  }
  __bf16* dst = btr + ((size_t)(rb * 32 + cg * 4 + ktl) * 64 + lane) * 32;
#pragma unroll
  for (int i = 0; i < 4; ++i)
    *(bf16x8*)(dst + i * 8) = *(bf16x8*)(outv + i * 8);
}

// ---------------------------------------------------------------- flash attention v9
// 4-wave blocks, 128 q-rows/block (32/wave), K/V tile shared via LDS (double-buffered
// global_load_lds), bias JIT per-wave from global, zero-shuffle fixed-shift softmax,
// K-split x2 with disjoint partials. LDS 48KB -> 3 blocks/CU (12 waves/CU).
#define STAGE(t, b) {                                                          \
  const char* _ks = kp + (size_t)(t) * 8192 + w * 2048 + lane * 16;            \
  const char* _vs = vp + (size_t)(t) * 8192 + w * 2048 + lane * 16;            \
  gld16(&Kb[b][w * 2048],        _ks);                                         \
  gld16(&Kb[b][w * 2048 + 1024], _ks + 1024);                                  \
  gld16(&Vb[b][w * 2048],        _vs);                                         \
  gld16(&Vb[b][w * 2048 + 1024], _vs + 1024);                                  \
}

#define COMPUTE(t, b) {                                                        \
  bf16x8 kf[4][2];                                                             \
  _Pragma("unroll")                                                            \
  for (int ni = 0; ni < 4; ++ni)                                               \
    _Pragma("unroll")                                                          \
    for (int ks = 0; ks < 2; ++ks)                                             \
      kf[ni][ks] = *(const bf16x8*)(&Kb[b][0] + ks * 4096 + (ni * 16 + c) * 64 + g * 16); \
  f32x4 sacc[2][4];                                                            \
  _Pragma("unroll")                                                            \
  for (int mi = 0; mi < 2; ++mi)                                               \
    _Pragma("unroll")                                                          \
    for (int ni = 0; ni < 4; ++ni) {                                           \
      f32x4 s_ = __builtin_amdgcn_mfma_f32_16x16x32_bf16(qf[mi][0], kf[ni][0], (f32x4)(0.0f), 0, 0, 0); \
      sacc[mi][ni] = __builtin_amdgcn_mfma_f32_16x16x32_bf16(qf[mi][1], kf[ni][1], s_, 0, 0, 0); \
    }                                                                          \
  const char* _bb = bp + ((size_t)(t) * 64 + lane) * 64;                       \
  bf16x8 bA[4];                                                                \
  _Pragma("unroll")                                                            \
  for (int i = 0; i < 4; ++i) bA[i] = *(const bf16x8*)(_bb + i * 16);          \
  _Pragma("unroll")                                                            \
  for (int mi = 0; mi < 2; ++mi)                                               \
    _Pragma("unroll")                                                          \
    for (int j = 0; j < 4; ++j) {                                              \
      const float p0 = __builtin_amdgcn_exp2f(sacc[mi][0][j] + (float)bA[(mi * 16 + 0 + j) >> 3][(mi * 16 + 0 + j) & 7]);  \
      const float p1 = __builtin_amdgcn_exp2f(sacc[mi][1][j] + (float)bA[(mi * 16 + 4 + j) >> 3][(mi * 16 + 4 + j) & 7]);  \
      const float p2 = __builtin_amdgcn_exp2f(sacc[mi][2][j] + (float)bA[(mi * 16 + 8 + j) >> 3][(mi * 16 + 8 + j) & 7]);  \
      const float p3 = __builtin_amdgcn_exp2f(sacc[mi][3][j] + (float)bA[(mi * 16 + 12 + j) >> 3][(mi * 16 + 12 + j) & 7]);\
      lsum[mi][j] += (p0 + p1) + (p2 + p3);                                    \
      bf16x4 pk;                                                               \
      pk[0] = (__bf16)p0; pk[1] = (__bf16)p1; pk[2] = (__bf16)p2; pk[3] = (__bf16)p3; \
      *(bf16x4*)&Ps[w][c >> 3][mi * 16 + g * 4 + j][(c & 7) * 4] = pk;         \
    }                                                                          \
  bf16x8 pf[2][2];                                                             \
  _Pragma("unroll")                                                            \
  for (int mi = 0; mi < 2; ++mi)                                               \
    _Pragma("unroll")                                                          \
    for (int ks = 0; ks < 2; ++ks)                                             \
      pf[mi][ks] = *(const bf16x8*)&Ps[w][ks][mi * 16 + c][g * 8];             \
  _Pragma("unroll")                                                            \
  for (int ni = 0; ni < 4; ++ni) {                                             \
    const bf16x8 v0 = *(const bf16x8*)(&Vb[b][0] + 0 * 4096 + ni * 1024 + c * 64 + g * 16); \
    const bf16x8 v1 = *(const bf16x8*)(&Vb[b][0] + 1 * 4096 + ni * 1024 + c * 64 + g * 16); \
    _Pragma("unroll")                                                          \
    for (int mi = 0; mi < 2; ++mi) {                                           \
      oacc[mi][ni] = __builtin_amdgcn_mfma_f32_16x16x32_bf16(pf[mi][0], v0, oacc[mi][ni], 0, 0, 0); \
      oacc[mi][ni] = __builtin_amdgcn_mfma_f32_16x16x32_bf16(pf[mi][1], v1, oacc[mi][ni], 0, 0, 0); \
    }                                                                          \
  }                                                                            \
}

__global__ __launch_bounds__(256, 3)
void attn_kernel(const __bf16* __restrict__ qb, const __bf16* __restrict__ ktp,
                 const __bf16* __restrict__ vtp, const __bf16* __restrict__ btr,
                 float* __restrict__ pO, float* __restrict__ pl) {
  __shared__ __attribute__((aligned(16))) char Kb[2][8192];
  __shared__ __attribute__((aligned(16))) char Vb[2][8192];
  __shared__ __attribute__((aligned(16))) __bf16 Ps[4][2][32][32];  // per-wave 4KB
  const int tid = threadIdx.x, w = tid >> 6, lane = tid & 63;
  const int c = lane & 15, g = lane >> 4;
  const int idx = blockIdx.x;                 // half*512 + rb*32 + bh
  const int bh = idx & 31, rb = (idx >> 5) & 15, half = idx >> 9;
  const __bf16* qh = qb + (size_t)bh * (2048 * 64);
  const char* kp = (const char*)ktp + (size_t)bh * (32 * 8192);
  const char* vp = (const char*)vtp + (size_t)bh * (32 * 8192);
  const int rb32 = rb * 4 + w;                // this wave's 32-row group (0..63)
  const char* bp = (const char*)btr + (size_t)rb32 * 131072;
  const int q0 = rb * 128 + w * 32;

  bf16x8 qf[2][2];
#pragma unroll
  for (int mi = 0; mi < 2; ++mi)
#pragma unroll
    for (int ks = 0; ks < 2; ++ks)
      qf[mi][ks] = *(const bf16x8*)(qh + (size_t)(q0 + mi * 16 + c) * 64 + ks * 32 + g * 8);

  f32x4 oacc[2][4];
  float lsum[2][4];
#pragma unroll
  for (int mi = 0; mi < 2; ++mi)
#pragma unroll
    for (int ni = 0; ni < 4; ++ni) oacc[mi][ni] = (f32x4)(0.0f);
#pragma unroll
  for (int mi = 0; mi < 2; ++mi)
#pragma unroll
    for (int j = 0; j < 4; ++j) lsum[mi][j] = 0.0f;

  const int t0 = half * 16;
  STAGE(t0, 0);
  __syncthreads();
#pragma unroll 1
  for (int tt = 0; tt < 16; tt += 2) {
    if (tt + 1 < 16) STAGE(t0 + tt + 1, 1);
    COMPUTE(t0 + tt, 0);
    __syncthreads();
    if (tt + 2 < 16) STAGE(t0 + tt + 2, 0);
    COMPUTE(t0 + tt + 1, 1);
    __syncthreads();
  }

  // disjoint partial stores: pO[half*32+bh][row][64], pl[half*32+bh][row]
  float* po  = pO + (((size_t)(half * 32 + bh)) * 2048 + q0) * 64;
  float* plp = pl + ((size_t)(half * 32 + bh)) * 2048 + q0;
#pragma unroll
  for (int mi = 0; mi < 2; ++mi)
#pragma unroll
    for (int j = 0; j < 4; ++j) {
      float l = lsum[mi][j];
      l += __shfl_xor(l, 1, 64);
      l += __shfl_xor(l, 2, 64);
      l += __shfl_xor(l, 4, 64);
      l += __shfl_xor(l, 8, 64);
      const int row = mi * 16 + g * 4 + j;
      if (c == 0) plp[row] = l;
#pragma unroll
      for (int ni = 0; ni < 4; ++ni)
        po[row * 64 + ni * 16 + c] = oacc[mi][ni][j];
    }
}

// ---------------------------------------------------------------- combine halves -> oupb bf16
__global__ __launch_bounds__(256)
void combine_kernel(const float* __restrict__ pO, const float* __restrict__ pl,
                    __bf16* __restrict__ oupb) {
  const int rg = blockIdx.x;
  const int bh = rg & 31, qt = rg >> 5;      // qt in [0,64): 32-row groups
  const int b2 = bh >> 4, h = bh & 15;
  const int tid = threadIdx.x;
  const int row = qt * 32 + (tid >> 3), hd0 = (tid & 7) * 8;
  const float l = pl[(size_t)bh * 2048 + row] + pl[(size_t)(32 + bh) * 2048 + row];
  const float inv = 1.0f / l;
  const float* p0 = pO + ((size_t)bh * 2048 + row) * 64 + hd0;
  const float* p1 = pO + ((size_t)(32 + bh) * 2048 + row) * 64 + hd0;
  const float4 a0 = *(const float4*)p0;
  const float4 b0 = *(const float4*)(p0 + 4);
  const float4 a1 = *(const float4*)p1;
  const float4 b1 = *(const float4*)(p1 + 4);
  bf16x8 o;
  o[0] = (__bf16)((a0.x + a1.x) * inv); o[1] = (__bf16)((a0.y + a1.y) * inv);
  o[2] = (__bf16)((a0.z + a1.z) * inv); o[3] = (__bf16)((a0.w + a1.w) * inv);
  o[4] = (__bf16)((b0.x + b1.x) * inv); o[5] = (__bf16)((b0.y + b1.y) * inv);
  o[6] = (__bf16)((b0.z + b1.z) * inv); o[7] = (__bf16)((b0.w + b1.w) * inv);
  *(bf16x8*)(oupb + ((size_t)(b2 * 2048 + row) * 16 + h) * 64 + hd0) = o;
}

// ---------------------------------------------------------------- proj GEMM (64x128 tiles)
__global__ __launch_bounds__(256, 2)
void gemm_proj_kernel(const __bf16* __restrict__ A, const __bf16* __restrict__ B,
                      const float* __restrict__ b_proj, float* __restrict__ out) {
  __shared__ __attribute__((aligned(16))) __bf16 As[64 * 32];
  __shared__ __attribute__((aligned(16))) __bf16 Bs[128 * 32];
  const int tid = threadIdx.x;
  const int w = tid >> 6, lane = tid & 63;
  const int c = lane & 15, g = lane >> 4;
  const int m0 = blockIdx.y * 64, n0 = blockIdx.x * 128;
  const int wm = (w >> 1) * 32, wn = (w & 1) * 64;
  f32x4 acc[2][4];
#pragma unroll
  for (int i = 0; i < 2; ++i)
#pragma unroll
    for (int j = 0; j < 4; ++j) acc[i][j] = (f32x4)(0.0f);

  const int r_row = lane >> 2;
  const int r_col = (lane & 3) * 16;
  const char* Abase = (const char*)A + (size_t)m0 * 2048;
  const char* Bbase = (const char*)B + (size_t)n0 * 2048;

  for (int kt = 0; kt < 1024; kt += 32) {
    {
      const int row = w * 16 + r_row;
      gld16((char*)As + w * 1024, Abase + (size_t)row * 2048 + kt * 2 + r_col);
    }
#pragma unroll
    for (int s = 0; s < 2; ++s) {
      const int R = w * 2 + s;
      const int row = R * 16 + r_row;
      gld16((char*)Bs + R * 1024, Bbase + (size_t)row * 2048 + kt * 2 + r_col);
    }
    __syncthreads();
    bf16x8 af[2], bfr[4];
#pragma unroll
    for (int i = 0; i < 2; ++i)
      af[i] = *(const bf16x8*)((const char*)As + (wm + i * 16 + c) * 64 + g * 16);
#pragma unroll
    for (int i = 0; i < 4; ++i)
      bfr[i] = *(const bf16x8*)((const char*)Bs + (wn + i * 16 + c) * 64 + g * 16);
#pragma unroll
    for (int mi = 0; mi < 2; ++mi)
#pragma unroll
      for (int ni = 0; ni < 4; ++ni)
        acc[mi][ni] = __builtin_amdgcn_mfma_f32_16x16x32_bf16(af[mi], bfr[ni], acc[mi][ni], 0, 0, 0);
    __syncthreads();
  }

  float cbias[4];
#pragma unroll
  for (int ni = 0; ni < 4; ++ni) cbias[ni] = b_proj[n0 + wn + ni * 16 + c];
#pragma unroll
  for (int mi = 0; mi < 2; ++mi)
#pragma unroll
    for (int j = 0; j < 4; ++j) {
      const int m = m0 + wm + mi * 16 + g * 4 + j;
      float* orow = out + (size_t)m * 1024 + n0 + wn;
#pragma unroll
      for (int ni = 0; ni < 4; ++ni)
        orow[ni * 16 + c] = acc[mi][ni][j] + cbias[ni];
    }
}

// ---------------------------------------------------------------- launch
extern "C" void kernel_launch(void* const* d_in, const int* in_sizes, int n_in,
                              void* d_out, int out_size, void* d_ws, size_t ws_size,
                              hipStream_t stream) {
  const float* x         = (const float*)d_in[0];
  const float* attn_bias = (const float*)d_in[1];
  const float* w_qkv     = (const float*)d_in[2];
  const float* q_bias    = (const float*)d_in[3];
  const float* v_bias    = (const float*)d_in[4];
  const float* scale_mul = (const float*)d_in[5];
  const float* w_proj    = (const float*)d_in[6];
  const float* b_proj    = (const float*)d_in[7];
  float* out = (float*)d_out;

  __bf16* xb     = (__bf16*)d_ws;                 // 8MB (aliased as oupb after gemm_qkv)
  __bf16* wqkvb  = xb + 4194304;                  // 6MB
  __bf16* wprojb = wqkvb + 3145728;               // 2MB
  __bf16* qb     = wprojb + 1048576;              // 8MB (q pre-scaled by log2e)
  __bf16* ktp    = qb + 4194304;                  // 8MB (K fragment-tile order)
  __bf16* vtp    = ktp + 4194304;                 // 8MB (V slot order)
  __bf16* btr    = vtp + 4194304;                 // 8MB (bias, *log2e)
  __bf16* vb     = btr + 4194304;                 // 8MB (V row order; dead after vtrans)
  float*  pO     = (float*)vb;                    // 32MB, aliases vb (attn runs after vtrans)
  float*  pl     = pO + 2 * 32 * 2048 * 64;       // 512KB
  __bf16* oupb   = xb;                            // alias: xb dead after gemm_qkv

  btrans_kernel<<<512, 256, 0, stream>>>(attn_bias, btr);
  cvt_all_kernel<<<8192, 256, 0, stream>>>(x, w_qkv, w_proj, xb, wqkvb, wprojb);

  gemm_qkv_kernel<<<dim3(24, 32), 256, 0, stream>>>(xb, wqkvb, q_bias, v_bias, scale_mul,
                                                    qb, ktp, vb);
  vtrans_kernel<<<256, 256, 0, stream>>>(vb, vtp);
  attn_kernel<<<1024, 256, 0, stream>>>(qb, ktp, vtp, btr, pO, pl);
  combine_kernel<<<2048, 256, 0, stream>>>(pO, pl, oupb);
  gemm_proj_kernel<<<dim3(8, 64), 256, 0, stream>>>(oupb, wprojb, b_proj, out);
}

// Round 9
// 225.976 us; speedup vs baseline: 1.2562x; 1.0109x over previous
//
#include <hip/hip_runtime.h>
#include <cstdint>
#include <cstddef>
#include <math.h>

typedef __attribute__((ext_vector_type(8))) __bf16 bf16x8;
typedef __attribute__((ext_vector_type(4))) __bf16 bf16x4;
typedef __attribute__((ext_vector_type(4))) float f32x4;

#define AS1 __attribute__((address_space(1)))
#define AS3 __attribute__((address_space(3)))

#define LOG2E 1.4426950408889634f

__device__ __forceinline__ void gld16(void* lds_uniform, const void* gaddr) {
  __builtin_amdgcn_global_load_lds((const AS1 unsigned int*)gaddr,
                                   (AS3 unsigned int*)lds_uniform, 16, 0, 0);
}

// ---------------------------------------------------------------- prep: fp32->bf16 casts + bias rearrange
__global__ __launch_bounds__(256)
void prep_kernel(const float* __restrict__ x, const float* __restrict__ wqkv,
                 const float* __restrict__ wproj, const float* __restrict__ bias,
                 __bf16* __restrict__ xb, __bf16* __restrict__ wqkvb,
                 __bf16* __restrict__ wprojb, __bf16* __restrict__ btr) {
  __shared__ __bf16 T[32][264];
  const int b = blockIdx.x;
  const int tid = threadIdx.x;
  if (b < 8192) {
    const float* src; __bf16* dst; int off;
    if (b < 4096)      { src = x;     dst = xb;     off = b; }
    else if (b < 7168) { src = wqkv;  dst = wqkvb;  off = b - 4096; }
    else               { src = wproj; dst = wprojb; off = b - 7168; }
    const int i = (off * 256 + tid) * 4;
    const float4 v = *(const float4*)(src + i);
    bf16x4 o;
    o[0] = (__bf16)v.x; o[1] = (__bf16)v.y; o[2] = (__bf16)v.z; o[3] = (__bf16)v.w;
    *(bf16x4*)(dst + i) = o;
    return;
  }
  const int bb = b - 8192;
  const int rb = bb >> 3, cg = bb & 7;
  const float* src = bias + (size_t)(rb * 32) * 2048 + cg * 256;
#pragma unroll
  for (int i = 0; i < 8; ++i) {
    const int u = i * 256 + tid;
    const int r = u >> 6, c4 = (u & 63) * 4;
    const float4 v = *(const float4*)(src + (size_t)r * 2048 + c4);
    T[r][c4 + 0] = (__bf16)(v.x * LOG2E);
    T[r][c4 + 1] = (__bf16)(v.y * LOG2E);
    T[r][c4 + 2] = (__bf16)(v.z * LOG2E);
    T[r][c4 + 3] = (__bf16)(v.w * LOG2E);
  }
  __syncthreads();
  const int ktl = tid >> 6;
  const int lane = tid & 63, g = lane >> 4, c = lane & 15;
  __bf16 outv[32];
#pragma unroll
  for (int v = 0; v < 32; ++v) {
    const int mi = v >> 4, ni = (v >> 2) & 3, j = v & 3;
    outv[v] = T[mi * 16 + g * 4 + j][ktl * 64 + ni * 16 + c];
  }
  __bf16* dst = btr + ((size_t)(rb * 32 + cg * 4 + ktl) * 64 + lane) * 32;
#pragma unroll
  for (int i = 0; i < 4; ++i)
    *(bf16x8*)(dst + i * 8) = *(bf16x8*)(outv + i * 8);
}

// ---------------------------------------------------------------- QKV GEMM (swapped-operand epilogue)
__global__ __launch_bounds__(256, 2)
void gemm_qkv_kernel(const __bf16* __restrict__ A, const __bf16* __restrict__ B,
                     const float* __restrict__ q_bias, const float* __restrict__ v_bias,
                     const float* __restrict__ scale_mul,
                     __bf16* __restrict__ qb, __bf16* __restrict__ ktp, __bf16* __restrict__ vb) {
  __shared__ __attribute__((aligned(16))) __bf16 As[128 * 32];
  __shared__ __attribute__((aligned(16))) __bf16 Bs[128 * 32];
  const int tid = threadIdx.x;
  const int w = tid >> 6, lane = tid & 63;
  const int m0 = blockIdx.y * 128, n0 = blockIdx.x * 128;
  const int wm = (w >> 1) * 64, wn = (w & 1) * 64;
  const int c = lane & 15, g = lane >> 4;
  f32x4 acc[4][4];  // [ni][mi]
#pragma unroll
  for (int i = 0; i < 4; ++i)
#pragma unroll
    for (int j = 0; j < 4; ++j) acc[i][j] = (f32x4)(0.0f);

  const int r_row = lane >> 2;
  const int r_col = (lane & 3) * 16;
  const char* Abase = (const char*)A + (size_t)m0 * 2048;
  const char* Bbase = (const char*)B + (size_t)n0 * 2048;

  for (int kt = 0; kt < 1024; kt += 32) {
#pragma unroll
    for (int s = 0; s < 2; ++s) {
      const int R = w * 2 + s;
      const int row = R * 16 + r_row;
      gld16((char*)As + R * 1024, Abase + (size_t)row * 2048 + kt * 2 + r_col);
      gld16((char*)Bs + R * 1024, Bbase + (size_t)row * 2048 + kt * 2 + r_col);
    }
    __syncthreads();
    bf16x8 af[4], bfr[4];
#pragma unroll
    for (int i = 0; i < 4; ++i) {
      af[i]  = *(const bf16x8*)((const char*)As + (wm + i * 16 + c) * 64 + g * 16);
      bfr[i] = *(const bf16x8*)((const char*)Bs + (wn + i * 16 + c) * 64 + g * 16);
    }
#pragma unroll
    for (int ni = 0; ni < 4; ++ni)
#pragma unroll
      for (int mi = 0; mi < 4; ++mi)
        acc[ni][mi] = __builtin_amdgcn_mfma_f32_16x16x32_bf16(bfr[ni], af[mi], acc[ni][mi], 0, 0, 0);
    __syncthreads();
  }

  const int nbase = n0 + wn;
  const int which = nbase >> 10;
  const int h = (nbase >> 6) & 15;
  float smh = 1.0f;
  if (which == 0) smh = __expf(fminf(scale_mul[h], 4.605170185988091f)) * LOG2E;
  float4 cb[4];
#pragma unroll
  for (int ni = 0; ni < 4; ++ni) {
    if (which == 0)      cb[ni] = *(const float4*)(q_bias + nbase + ni * 16 + 4 * g);
    else if (which == 2) cb[ni] = *(const float4*)(v_bias + nbase - 2048 + ni * 16 + 4 * g);
    else                 cb[ni] = make_float4(0.f, 0.f, 0.f, 0.f);
  }
  const int mrow0 = m0 + wm;
  const int b2 = mrow0 >> 11;
  const int lpos0 = mrow0 & 2047;
  __bf16* kt_tile = ktp + (size_t)(b2 * 16 + h) * 131072 + (size_t)(lpos0 >> 6) * 4096;
  __bf16* dst_qv = ((which == 0) ? qb : vb) + ((size_t)((b2 * 16 + h) * 2048 + lpos0)) * 64;

#pragma unroll
  for (int mi = 0; mi < 4; ++mi) {
    float v[4][4];
    float ss = 0.0f;
#pragma unroll
    for (int ni = 0; ni < 4; ++ni) {
      v[ni][0] = acc[ni][mi][0] + cb[ni].x;
      v[ni][1] = acc[ni][mi][1] + cb[ni].y;
      v[ni][2] = acc[ni][mi][2] + cb[ni].z;
      v[ni][3] = acc[ni][mi][3] + cb[ni].w;
#pragma unroll
      for (int j = 0; j < 4; ++j) ss += v[ni][j] * v[ni][j];
    }
    ss += __shfl_xor(ss, 16, 64);
    ss += __shfl_xor(ss, 32, 64);
    const float sc = (which == 2) ? 1.0f : (rsqrtf(ss) * smh);
    const int key = mi * 16 + c;
    if (which == 1) {
#pragma unroll
      for (int ni = 0; ni < 4; ++ni) {
        bf16x4 pk;
        pk[0] = (__bf16)(v[ni][0] * sc); pk[1] = (__bf16)(v[ni][1] * sc);
        pk[2] = (__bf16)(v[ni][2] * sc); pk[3] = (__bf16)(v[ni][3] * sc);
        *(bf16x4*)(kt_tile + (ni >> 1) * 2048 + key * 32 + (ni & 1) * 16 + 4 * g) = pk;
      }
    } else {
      __bf16* drow = dst_qv + (size_t)key * 64;
#pragma unroll
      for (int ni = 0; ni < 4; ++ni) {
        bf16x4 pk;
        pk[0] = (__bf16)(v[ni][0] * sc); pk[1] = (__bf16)(v[ni][1] * sc);
        pk[2] = (__bf16)(v[ni][2] * sc); pk[3] = (__bf16)(v[ni][3] * sc);
        *(bf16x4*)(drow + ni * 16 + 4 * g) = pk;
      }
    }
  }
}

// ---------------------------------------------------------------- V transpose to tile-slot layout
__global__ __launch_bounds__(256)
void vtrans_kernel(const __bf16* __restrict__ vb, __bf16* __restrict__ vtp) {
  __shared__ __attribute__((aligned(16))) __bf16 Vs[4][64 * 64];
  const int w = threadIdx.x >> 6, lane = threadIdx.x & 63;
  const int idx = blockIdx.x * 4 + w;
  const int bh = idx >> 5, tile = idx & 31;
  const __bf16* src = vb + ((size_t)bh * 2048 + tile * 64) * 64;
#pragma unroll
  for (int s = 0; s < 8; ++s)
    gld16((char*)&Vs[w][0] + s * 1024, (const char*)src + s * 1024 + lane * 16);
  __syncthreads();
  __bf16* outb = vtp + (size_t)idx * 4096;
#pragma unroll
  for (int r = 0; r < 8; ++r) {
    const int o = r * 512 + lane * 8;
    const int hd = (o >> 5) & 63;
    const int sl0 = ((o >> 11) << 5) | (o & 31);
    bf16x8 pk;
#pragma unroll
    for (int i = 0; i < 8; ++i) {
      const int slot = sl0 + i;
      const int key = (slot & 3) * 16 + (slot >> 2);
      pk[i] = Vs[w][key * 64 + hd];
    }
    *(bf16x8*)(outb + o) = pk;
  }
}

// ---------------------------------------------------------------- flash attention v10
// 4-wave blocks, 128 q-rows, full 2048 keys (no K-split), LDS-shared K/V dbuf,
// Ps padded to 40 elem rows (80B) to break the 8-way bank conflict, bf16 output direct.
#define STAGE(t, b) {                                                          \
  const char* _ks = kp + (size_t)(t) * 8192 + w * 2048 + lane * 16;            \
  const char* _vs = vp + (size_t)(t) * 8192 + w * 2048 + lane * 16;            \
  gld16(&Kb[b][w * 2048],        _ks);                                         \
  gld16(&Kb[b][w * 2048 + 1024], _ks + 1024);                                  \
  gld16(&Vb[b][w * 2048],        _vs);                                         \
  gld16(&Vb[b][w * 2048 + 1024], _vs + 1024);                                  \
}

#define COMPUTE(t, b) {                                                        \
  bf16x8 kf[4][2];                                                             \
  _Pragma("unroll")                                                            \
  for (int ni = 0; ni < 4; ++ni)                                               \
    _Pragma("unroll")                                                          \
    for (int ks = 0; ks < 2; ++ks)                                             \
      kf[ni][ks] = *(const bf16x8*)(&Kb[b][0] + ks * 4096 + (ni * 16 + c) * 64 + g * 16); \
  f32x4 sacc[2][4];                                                            \
  _Pragma("unroll")                                                            \
  for (int mi = 0; mi < 2; ++mi)                                               \
    _Pragma("unroll")                                                          \
    for (int ni = 0; ni < 4; ++ni) {                                           \
      f32x4 s_ = __builtin_amdgcn_mfma_f32_16x16x32_bf16(qf[mi][0], kf[ni][0], (f32x4)(0.0f), 0, 0, 0); \
      sacc[mi][ni] = __builtin_amdgcn_mfma_f32_16x16x32_bf16(qf[mi][1], kf[ni][1], s_, 0, 0, 0); \
    }                                                                          \
  const char* _bb = bp + ((size_t)(t) * 64 + lane) * 64;                       \
  bf16x8 bA[4];                                                                \
  _Pragma("unroll")                                                            \
  for (int i = 0; i < 4; ++i) bA[i] = *(const bf16x8*)(_bb + i * 16);          \
  _Pragma("unroll")                                                            \
  for (int mi = 0; mi < 2; ++mi)                                               \
    _Pragma("unroll")                                                          \
    for (int j = 0; j < 4; ++j) {                                              \
      const float p0 = __builtin_amdgcn_exp2f(sacc[mi][0][j] + (float)bA[(mi * 16 + 0 + j) >> 3][(mi * 16 + 0 + j) & 7]);  \
      const float p1 = __builtin_amdgcn_exp2f(sacc[mi][1][j] + (float)bA[(mi * 16 + 4 + j) >> 3][(mi * 16 + 4 + j) & 7]);  \
      const float p2 = __builtin_amdgcn_exp2f(sacc[mi][2][j] + (float)bA[(mi * 16 + 8 + j) >> 3][(mi * 16 + 8 + j) & 7]);  \
      const float p3 = __builtin_amdgcn_exp2f(sacc[mi][3][j] + (float)bA[(mi * 16 + 12 + j) >> 3][(mi * 16 + 12 + j) & 7]);\
      lsum[mi][j] += (p0 + p1) + (p2 + p3);                                    \
      bf16x4 pk;                                                               \
      pk[0] = (__bf16)p0; pk[1] = (__bf16)p1; pk[2] = (__bf16)p2; pk[3] = (__bf16)p3; \
      *(bf16x4*)&Ps[w][c >> 3][mi * 16 + g * 4 + j][(c & 7) * 4] = pk;         \
    }                                                                          \
  bf16x8 pf[2][2];                                                             \
  _Pragma("unroll")                                                            \
  for (int mi = 0; mi < 2; ++mi)                                               \
    _Pragma("unroll")                                                          \
    for (int ks = 0; ks < 2; ++ks)                                             \
      pf[mi][ks] = *(const bf16x8*)&Ps[w][ks][mi * 16 + c][g * 8];             \
  _Pragma("unroll")                                                            \
  for (int ni = 0; ni < 4; ++ni) {                                             \
    const bf16x8 v0 = *(const bf16x8*)(&Vb[b][0] + 0 * 4096 + ni * 1024 + c * 64 + g * 16); \
    const bf16x8 v1 = *(const bf16x8*)(&Vb[b][0] + 1 * 4096 + ni * 1024 + c * 64 + g * 16); \
    _Pragma("unroll")                                                          \
    for (int mi = 0; mi < 2; ++mi) {                                           \
      oacc[mi][ni] = __builtin_amdgcn_mfma_f32_16x16x32_bf16(pf[mi][0], v0, oacc[mi][ni], 0, 0, 0); \
      oacc[mi][ni] = __builtin_amdgcn_mfma_f32_16x16x32_bf16(pf[mi][1], v1, oacc[mi][ni], 0, 0, 0); \
    }                                                                          \
  }                                                                            \
}

__global__ __launch_bounds__(256, 3)
void attn_kernel(const __bf16* __restrict__ qb, const __bf16* __restrict__ ktp,
                 const __bf16* __restrict__ vtp, const __bf16* __restrict__ btr,
                 __bf16* __restrict__ oupb) {
  __shared__ __attribute__((aligned(16))) char Kb[2][8192];
  __shared__ __attribute__((aligned(16))) char Vb[2][8192];
  __shared__ __attribute__((aligned(16))) __bf16 Ps[4][2][32][40];  // 40-elem rows: 80B stride
  const int tid = threadIdx.x, w = tid >> 6, lane = tid & 63;
  const int c = lane & 15, g = lane >> 4;
  const int idx = blockIdx.x;                 // rb*32 + bh  (bh fastest: <=4 bh per XCD)
  const int bh = idx & 31, rb = idx >> 5;
  const __bf16* qh = qb + (size_t)bh * (2048 * 64);
  const char* kp = (const char*)ktp + (size_t)bh * (32 * 8192);
  const char* vp = (const char*)vtp + (size_t)bh * (32 * 8192);
  const int rb32 = rb * 4 + w;
  const char* bp = (const char*)btr + (size_t)rb32 * 131072;
  const int q0 = rb * 128 + w * 32;
  const int b2 = bh >> 4, h = bh & 15;

  bf16x8 qf[2][2];
#pragma unroll
  for (int mi = 0; mi < 2; ++mi)
#pragma unroll
    for (int ks = 0; ks < 2; ++ks)
      qf[mi][ks] = *(const bf16x8*)(qh + (size_t)(q0 + mi * 16 + c) * 64 + ks * 32 + g * 8);

  f32x4 oacc[2][4];
  float lsum[2][4];
#pragma unroll
  for (int mi = 0; mi < 2; ++mi)
#pragma unroll
    for (int ni = 0; ni < 4; ++ni) oacc[mi][ni] = (f32x4)(0.0f);
#pragma unroll
  for (int mi = 0; mi < 2; ++mi)
#pragma unroll
    for (int j = 0; j < 4; ++j) lsum[mi][j] = 0.0f;

  STAGE(0, 0);
  __syncthreads();
#pragma unroll 1
  for (int tt = 0; tt < 32; tt += 2) {
    if (tt + 1 < 32) STAGE(tt + 1, 1);
    COMPUTE(tt, 0);
    __syncthreads();
    if (tt + 2 < 32) STAGE(tt + 2, 0);
    COMPUTE(tt + 1, 1);
    __syncthreads();
  }

  // normalize + write bf16 [B, L, H*HD]
#pragma unroll
  for (int mi = 0; mi < 2; ++mi)
#pragma unroll
    for (int j = 0; j < 4; ++j) {
      float l = lsum[mi][j];
      l += __shfl_xor(l, 1, 64);
      l += __shfl_xor(l, 2, 64);
      l += __shfl_xor(l, 4, 64);
      l += __shfl_xor(l, 8, 64);
      const float inv = 1.0f / l;
      const int qrow = q0 + mi * 16 + g * 4 + j;
      __bf16* orow = oupb + ((size_t)(b2 * 2048 + qrow) * 16 + h) * 64;
#pragma unroll
      for (int ni = 0; ni < 4; ++ni)
        orow[ni * 16 + c] = (__bf16)(oacc[mi][ni][j] * inv);
    }
}

// ---------------------------------------------------------------- proj GEMM (64x128 tiles)
__global__ __launch_bounds__(256, 2)
void gemm_proj_kernel(const __bf16* __restrict__ A, const __bf16* __restrict__ B,
                      const float* __restrict__ b_proj, float* __restrict__ out) {
  __shared__ __attribute__((aligned(16))) __bf16 As[64 * 32];
  __shared__ __attribute__((aligned(16))) __bf16 Bs[128 * 32];
  const int tid = threadIdx.x;
  const int w = tid >> 6, lane = tid & 63;
  const int c = lane & 15, g = lane >> 4;
  const int m0 = blockIdx.y * 64, n0 = blockIdx.x * 128;
  const int wm = (w >> 1) * 32, wn = (w & 1) * 64;
  f32x4 acc[2][4];
#pragma unroll
  for (int i = 0; i < 2; ++i)
#pragma unroll
    for (int j = 0; j < 4; ++j) acc[i][j] = (f32x4)(0.0f);

  const int r_row = lane >> 2;
  const int r_col = (lane & 3) * 16;
  const char* Abase = (const char*)A + (size_t)m0 * 2048;
  const char* Bbase = (const char*)B + (size_t)n0 * 2048;

  for (int kt = 0; kt < 1024; kt += 32) {
    {
      const int row = w * 16 + r_row;
      gld16((char*)As + w * 1024, Abase + (size_t)row * 2048 + kt * 2 + r_col);
    }
#pragma unroll
    for (int s = 0; s < 2; ++s) {
      const int R = w * 2 + s;
      const int row = R * 16 + r_row;
      gld16((char*)Bs + R * 1024, Bbase + (size_t)row * 2048 + kt * 2 + r_col);
    }
    __syncthreads();
    bf16x8 af[2], bfr[4];
#pragma unroll
    for (int i = 0; i < 2; ++i)
      af[i] = *(const bf16x8*)((const char*)As + (wm + i * 16 + c) * 64 + g * 16);
#pragma unroll
    for (int i = 0; i < 4; ++i)
      bfr[i] = *(const bf16x8*)((const char*)Bs + (wn + i * 16 + c) * 64 + g * 16);
#pragma unroll
    for (int mi = 0; mi < 2; ++mi)
#pragma unroll
      for (int ni = 0; ni < 4; ++ni)
        acc[mi][ni] = __builtin_amdgcn_mfma_f32_16x16x32_bf16(af[mi], bfr[ni], acc[mi][ni], 0, 0, 0);
    __syncthreads();
  }

  float cbias[4];
#pragma unroll
  for (int ni = 0; ni < 4; ++ni) cbias[ni] = b_proj[n0 + wn + ni * 16 + c];
#pragma unroll
  for (int mi = 0; mi < 2; ++mi)
#pragma unroll
    for (int j = 0; j < 4; ++j) {
      const int m = m0 + wm + mi * 16 + g * 4 + j;
      float* orow = out + (size_t)m * 1024 + n0 + wn;
#pragma unroll
      for (int ni = 0; ni < 4; ++ni)
        orow[ni * 16 + c] = acc[mi][ni][j] + cbias[ni];
    }
}

// ---------------------------------------------------------------- launch
extern "C" void kernel_launch(void* const* d_in, const int* in_sizes, int n_in,
                              void* d_out, int out_size, void* d_ws, size_t ws_size,
                              hipStream_t stream) {
  const float* x         = (const float*)d_in[0];
  const float* attn_bias = (const float*)d_in[1];
  const float* w_qkv     = (const float*)d_in[2];
  const float* q_bias    = (const float*)d_in[3];
  const float* v_bias    = (const float*)d_in[4];
  const float* scale_mul = (const float*)d_in[5];
  const float* w_proj    = (const float*)d_in[6];
  const float* b_proj    = (const float*)d_in[7];
  float* out = (float*)d_out;

  __bf16* xb     = (__bf16*)d_ws;                 // 8MB (aliased as oupb after gemm_qkv)
  __bf16* wqkvb  = xb + 4194304;                  // 6MB
  __bf16* wprojb = wqkvb + 3145728;               // 2MB
  __bf16* qb     = wprojb + 1048576;              // 8MB (q pre-scaled by log2e)
  __bf16* ktp    = qb + 4194304;                  // 8MB (K fragment-tile order)
  __bf16* vtp    = ktp + 4194304;                 // 8MB (V slot order)
  __bf16* btr    = vtp + 4194304;                 // 8MB (bias, *log2e)
  __bf16* vb     = btr + 4194304;                 // 8MB (V row order; dead after vtrans)
  __bf16* oupb   = xb;                            // alias: xb dead after gemm_qkv

  prep_kernel<<<8704, 256, 0, stream>>>(x, w_qkv, w_proj, attn_bias, xb, wqkvb, wprojb, btr);
  gemm_qkv_kernel<<<dim3(24, 32), 256, 0, stream>>>(xb, wqkvb, q_bias, v_bias, scale_mul,
                                                    qb, ktp, vb);
  vtrans_kernel<<<256, 256, 0, stream>>>(vb, vtp);
  attn_kernel<<<512, 256, 0, stream>>>(qb, ktp, vtp, btr, oupb);
  gemm_proj_kernel<<<dim3(8, 64), 256, 0, stream>>>(oupb, wprojb, b_proj, out);
}